// Round 7
// baseline (229.720 us; speedup 1.0000x reference)
//
#include <hip/hip_runtime.h>
#include <math.h>

#define B  8
#define T  16
#define C  64
#define H  56
#define W  56
#define HW (H*W)          // 3136
#define HW4 (HW/4)        // 784
#define DS 8
#define DIN (DS*DS)       // 64
#define DOUT 32
#define BC (B*C)          // 512

typedef float vfloat4 __attribute__((ext_vector_type(4)));

// ---------------------------------------------------------------------------
// R6 -> R7: R6 proved K3's load-dedup/att-b128 rework was NEUTRAL (211.7 ->
// 211.6), so those weren't on the critical path. Our 3 kernels total ~83 us
// vs ~45-50 us floor; fills (~120 us) hide per-kernel timing. This round
// deletes the glue: K2 (att) is merged INTO the apply kernel — each
// (n,chunk) block recomputes q/k/logits/softmax from pooled redundantly
// (~150 KFLOP per n x7 = 3.4 us grid-wide VALU) in exchange for one fewer
// launch, no att global round-trip, and K2's ~4-5 us. pooled moves to d_ws
// (out-head reuse would now race with apply's own stores).
// ---------------------------------------------------------------------------

// K1: pool. Block per (n,t): 8192 blocks x 256 thr, 13.5 KB LDS -> 8
// blocks/CU. Stage one t-slice (12.25 KB); wave q handles rows {2q,2q+1}
// (q<3) or {6} (q=3) of every 7x7 window -> wave-uniform; xs reads are
// 2-way bank-aliased (free). Partials combined via 1 KB LDS.
__global__ __launch_bounds__(256) void pool_kernel(const float* __restrict__ x,
                                                   float* __restrict__ pooled_g) {
    __shared__ float xs[HW];      // 12544 B
    __shared__ float part[256];   // 1 KB
    const int n = blockIdx.x;     // b*C + c
    const int t = blockIdx.y;
    const int tid = threadIdx.x;
    const int b = n >> 6;
    const int c = n & 63;

    const float4* x4 = (const float4*)x;
    float4* xs4 = (float4*)xs;
    const size_t base = ((size_t)(b * T + t) * C + c) * HW4;

    for (int i = tid; i < HW4; i += 256) xs4[i] = x4[base + i];
    __syncthreads();

    {
        const int wi = tid & 63;      // window = ri*8+rj
        const int q  = tid >> 6;      // wave index -> row group (uniform)
        const int ri = wi >> 3;
        const int rj = wi & 7;
        const int r0 = 2 * q;
        const int nrows = (q < 3) ? 2 : 1;
        float s = 0.f;
        for (int dr = 0; dr < nrows; ++dr) {
            const int row = 7 * ri + r0 + dr;
            const int col0 = 7 * rj;
            #pragma unroll
            for (int dj = 0; dj < 7; ++dj) s += xs[row * W + col0 + dj];
        }
        part[q * 64 + wi] = s;
    }
    __syncthreads();

    if (tid < 64) {
        const float v = part[tid] + part[tid + 64] + part[tid + 128] + part[tid + 192];
        pooled_g[((size_t)n * T + t) * DIN + tid] = v * (1.0f / 49.0f);
    }
}

// K2': att + apply fused. Grid (512,7) x 128 thr.
// Prologue (~10 KB LDS, redundant x7 per n, cheap): pooled (4 KB, L2-hot)
// -> q/k (4 outputs/thread) -> logits (2/thread) -> softmax (16 lanes) ->
// att_tr[s][t] in LDS. Apply: lanes 0..111 own ONE float4 column and ALL
// 16 t's (acc[16] float4 = 64 VGPR, no duplicated x loads); att read as
// broadcast ds_read_b128. x reads L3-warm (K1 just streamed x, 102.8 MB
// < 256 MB LLC; only ~2.5 MB touched in between). NT stores keep out from
// evicting x.
__global__ __launch_bounds__(128) void att_apply_kernel(const float* __restrict__ x,
                                                        const float* __restrict__ pooled_g,
                                                        const float* __restrict__ Wq,
                                                        const float* __restrict__ bq,
                                                        const float* __restrict__ Wk,
                                                        const float* __restrict__ bk,
                                                        float* __restrict__ out) {
    __shared__ float pooled_s[T * DIN];   // 4 KB
    __shared__ float qs[T * 33];          // padded stride 33
    __shared__ float ksh[T * 33];
    __shared__ float att_s[T * T];        // logits
    __shared__ float att_tr[T * T];       // probs, transposed [s][t]

    const int n = blockIdx.x;             // [0,512)
    const int chunk = blockIdx.y;         // [0,7)
    const int tid = threadIdx.x;
    const int b = n >> 6;
    const int c = n & 63;

    // pooled: 1024 floats = 256 float4, 2 per thread
    {
        const float4* pg4 = (const float4*)(pooled_g + (size_t)n * (T * DIN));
        float4* ps4 = (float4*)pooled_s;
        ps4[tid] = pg4[tid];
        ps4[tid + 128] = pg4[tid + 128];
    }
    __syncthreads();

    // q/k: 512 outputs, 4 per thread (weights from global: L1/L2 broadcast)
    #pragma unroll
    for (int j = 0; j < 4; ++j) {
        const int e = tid + 128 * j;
        const int t = e >> 5;
        const int d = e & 31;
        float sq = bq[d];
        float sk = bk[d];
        #pragma unroll 8
        for (int kk = 0; kk < DIN; ++kk) {
            const float f = pooled_s[t * DIN + kk];
            sq = fmaf(f, Wq[kk * DOUT + d], sq);
            sk = fmaf(f, Wk[kk * DOUT + d], sk);
        }
        qs[t * 33 + d] = sq;
        ksh[t * 33 + d] = sk;
    }
    __syncthreads();

    // logits: 256 outputs, 2 per thread
    #pragma unroll
    for (int j = 0; j < 2; ++j) {
        const int e = tid + 128 * j;
        const int tt = e >> 4;
        const int ss = e & 15;
        float s = 0.f;
        #pragma unroll
        for (int d = 0; d < DOUT; ++d) s = fmaf(qs[tt * 33 + d], ksh[ss * 33 + d], s);
        att_s[e] = s * 0.25f;             // 1/sqrt(16)
    }
    __syncthreads();

    // softmax rows (16 lanes), write transposed [s][t]
    if (tid < T) {
        const int r = tid;
        float m = -INFINITY;
        #pragma unroll
        for (int s = 0; s < T; ++s) m = fmaxf(m, att_s[r * T + s]);
        float e[T];
        float sum = 0.f;
        #pragma unroll
        for (int s = 0; s < T; ++s) { e[s] = __expf(att_s[r * T + s] - m); sum += e[s]; }
        const float inv = 1.0f / sum;
        #pragma unroll
        for (int s = 0; s < T; ++s) att_tr[s * T + r] = e[s] * inv;  // banks r+16(s&1)
    }
    __syncthreads();

    // apply: out[t,col] = sum_s att[t][s] * x[s,col]
    if (tid < 112) {
        const float4* x4 = (const float4*)x;
        float4* o4 = (float4*)out;
        const float4* att4 = (const float4*)att_tr;   // att4[s*4+q] = att[4q..4q+3][s]
        const size_t xbase = ((size_t)(b * T) * C + c) * HW4;
        const size_t tstride = (size_t)C * HW4;
        const int p4 = chunk * 112 + tid;

        float4 acc[16];
        #pragma unroll
        for (int t = 0; t < 16; ++t) acc[t] = make_float4(0.f, 0.f, 0.f, 0.f);

        #pragma unroll 4
        for (int s = 0; s < T; ++s) {
            const float4 xv = x4[xbase + (size_t)s * tstride + p4];
            #pragma unroll
            for (int q = 0; q < 4; ++q) {
                const float4 a = att4[s * 4 + q];     // broadcast ds_read_b128
                acc[q*4+0].x = fmaf(a.x, xv.x, acc[q*4+0].x);
                acc[q*4+0].y = fmaf(a.x, xv.y, acc[q*4+0].y);
                acc[q*4+0].z = fmaf(a.x, xv.z, acc[q*4+0].z);
                acc[q*4+0].w = fmaf(a.x, xv.w, acc[q*4+0].w);
                acc[q*4+1].x = fmaf(a.y, xv.x, acc[q*4+1].x);
                acc[q*4+1].y = fmaf(a.y, xv.y, acc[q*4+1].y);
                acc[q*4+1].z = fmaf(a.y, xv.z, acc[q*4+1].z);
                acc[q*4+1].w = fmaf(a.y, xv.w, acc[q*4+1].w);
                acc[q*4+2].x = fmaf(a.z, xv.x, acc[q*4+2].x);
                acc[q*4+2].y = fmaf(a.z, xv.y, acc[q*4+2].y);
                acc[q*4+2].z = fmaf(a.z, xv.z, acc[q*4+2].z);
                acc[q*4+2].w = fmaf(a.z, xv.w, acc[q*4+2].w);
                acc[q*4+3].x = fmaf(a.w, xv.x, acc[q*4+3].x);
                acc[q*4+3].y = fmaf(a.w, xv.y, acc[q*4+3].y);
                acc[q*4+3].z = fmaf(a.w, xv.z, acc[q*4+3].z);
                acc[q*4+3].w = fmaf(a.w, xv.w, acc[q*4+3].w);
            }
        }

        #pragma unroll
        for (int t = 0; t < 16; ++t) {
            vfloat4* dst = (vfloat4*)&o4[xbase + (size_t)t * tstride + p4];
            vfloat4 v; v.x = acc[t].x; v.y = acc[t].y; v.z = acc[t].z; v.w = acc[t].w;
            __builtin_nontemporal_store(v, dst);
        }
    }
}

extern "C" void kernel_launch(void* const* d_in, const int* in_sizes, int n_in,
                              void* d_out, int out_size, void* d_ws, size_t ws_size,
                              hipStream_t stream) {
    const float* x  = (const float*)d_in[0];
    const float* Wq = (const float*)d_in[1];
    const float* bq = (const float*)d_in[2];
    const float* Wk = (const float*)d_in[3];
    const float* bk = (const float*)d_in[4];
    float* out = (float*)d_out;

    // pooled (2 MB) in workspace — must NOT alias out now that apply writes
    // out in the same kernel that reads pooled.
    float* pooled_g = (float*)d_ws;

    pool_kernel<<<dim3(BC, T), dim3(256), 0, stream>>>(x, pooled_g);
    att_apply_kernel<<<dim3(BC, 7), dim3(128), 0, stream>>>(x, pooled_g, Wq, bq, Wk, bk, out);
}

// Round 8
// 226.733 us; speedup vs baseline: 1.0132x; 1.0132x over previous
//
#include <hip/hip_runtime.h>
#include <math.h>

#define B  8
#define T  16
#define C  64
#define H  56
#define W  56
#define HW (H*W)          // 3136
#define HW4 (HW/4)        // 784
#define DS 8
#define DIN (DS*DS)       // 64
#define DOUT 32
#define BC (B*C)          // 512

typedef float vfloat4 __attribute__((ext_vector_type(4)));

// ---------------------------------------------------------------------------
// R7 -> R8: R7's counters isolated att_apply = 64.5 us vs a 24 us HBM floor
// (2.4 TB/s, VALUBusy 24%, Occ 30% -> latency-bound). The apply s-loop held
// only 4 loads in flight (unroll 4). This round: hoist ALL 16 xv loads into
// xv[16] (static indices, fully unrolled) before the FMA block -> 16
// outstanding loads/thread (4x MLP). acc stays in AGPRs (R7 VGPR_Count=52
// proves compiler AGPR-allocates acc), xv adds ~64 VGPR -> ~3 waves/SIMD.
// K1 unchanged (single-variable attribution).
// ---------------------------------------------------------------------------

// K1: pool. Block per (n,t): 8192 blocks x 256 thr, 13.5 KB LDS -> 8
// blocks/CU. Stage one t-slice (12.25 KB); wave q handles rows {2q,2q+1}
// (q<3) or {6} (q=3) of every 7x7 window -> wave-uniform; xs reads are
// 2-way bank-aliased (free). Partials combined via 1 KB LDS.
__global__ __launch_bounds__(256) void pool_kernel(const float* __restrict__ x,
                                                   float* __restrict__ pooled_g) {
    __shared__ float xs[HW];      // 12544 B
    __shared__ float part[256];   // 1 KB
    const int n = blockIdx.x;     // b*C + c
    const int t = blockIdx.y;
    const int tid = threadIdx.x;
    const int b = n >> 6;
    const int c = n & 63;

    const float4* x4 = (const float4*)x;
    float4* xs4 = (float4*)xs;
    const size_t base = ((size_t)(b * T + t) * C + c) * HW4;

    for (int i = tid; i < HW4; i += 256) xs4[i] = x4[base + i];
    __syncthreads();

    {
        const int wi = tid & 63;      // window = ri*8+rj
        const int q  = tid >> 6;      // wave index -> row group (uniform)
        const int ri = wi >> 3;
        const int rj = wi & 7;
        const int r0 = 2 * q;
        const int nrows = (q < 3) ? 2 : 1;
        float s = 0.f;
        for (int dr = 0; dr < nrows; ++dr) {
            const int row = 7 * ri + r0 + dr;
            const int col0 = 7 * rj;
            #pragma unroll
            for (int dj = 0; dj < 7; ++dj) s += xs[row * W + col0 + dj];
        }
        part[q * 64 + wi] = s;
    }
    __syncthreads();

    if (tid < 64) {
        const float v = part[tid] + part[tid + 64] + part[tid + 128] + part[tid + 192];
        pooled_g[((size_t)n * T + t) * DIN + tid] = v * (1.0f / 49.0f);
    }
}

// K2': att + apply fused. Grid (512,7) x 128 thr.
// Prologue (~10 KB LDS, redundant x7 per n, ~3.4 us grid-wide): pooled ->
// q/k -> logits -> softmax -> att_tr[s][t] in LDS. Apply: lanes 0..111 own
// ONE float4 column and ALL 16 t's; xv[16] loaded UPFRONT (16 loads in
// flight), then 1024 FMA reading att via broadcast ds_read_b128. NT stores.
__global__ __launch_bounds__(128) void att_apply_kernel(const float* __restrict__ x,
                                                        const float* __restrict__ pooled_g,
                                                        const float* __restrict__ Wq,
                                                        const float* __restrict__ bq,
                                                        const float* __restrict__ Wk,
                                                        const float* __restrict__ bk,
                                                        float* __restrict__ out) {
    __shared__ float pooled_s[T * DIN];   // 4 KB
    __shared__ float qs[T * 33];          // padded stride 33
    __shared__ float ksh[T * 33];
    __shared__ float att_s[T * T];        // logits
    __shared__ float att_tr[T * T];       // probs, transposed [s][t]

    const int n = blockIdx.x;             // [0,512)
    const int chunk = blockIdx.y;         // [0,7)
    const int tid = threadIdx.x;
    const int b = n >> 6;
    const int c = n & 63;

    // pooled: 1024 floats = 256 float4, 2 per thread
    {
        const float4* pg4 = (const float4*)(pooled_g + (size_t)n * (T * DIN));
        float4* ps4 = (float4*)pooled_s;
        ps4[tid] = pg4[tid];
        ps4[tid + 128] = pg4[tid + 128];
    }
    __syncthreads();

    // q/k: 512 outputs, 4 per thread (weights from global: L1/L2 broadcast)
    #pragma unroll
    for (int j = 0; j < 4; ++j) {
        const int e = tid + 128 * j;
        const int t = e >> 5;
        const int d = e & 31;
        float sq = bq[d];
        float sk = bk[d];
        #pragma unroll 8
        for (int kk = 0; kk < DIN; ++kk) {
            const float f = pooled_s[t * DIN + kk];
            sq = fmaf(f, Wq[kk * DOUT + d], sq);
            sk = fmaf(f, Wk[kk * DOUT + d], sk);
        }
        qs[t * 33 + d] = sq;
        ksh[t * 33 + d] = sk;
    }
    __syncthreads();

    // logits: 256 outputs, 2 per thread
    #pragma unroll
    for (int j = 0; j < 2; ++j) {
        const int e = tid + 128 * j;
        const int tt = e >> 4;
        const int ss = e & 15;
        float s = 0.f;
        #pragma unroll
        for (int d = 0; d < DOUT; ++d) s = fmaf(qs[tt * 33 + d], ksh[ss * 33 + d], s);
        att_s[e] = s * 0.25f;             // 1/sqrt(16)
    }
    __syncthreads();

    // softmax rows (16 lanes), write transposed [s][t]
    if (tid < T) {
        const int r = tid;
        float m = -INFINITY;
        #pragma unroll
        for (int s = 0; s < T; ++s) m = fmaxf(m, att_s[r * T + s]);
        float e[T];
        float sum = 0.f;
        #pragma unroll
        for (int s = 0; s < T; ++s) { e[s] = __expf(att_s[r * T + s] - m); sum += e[s]; }
        const float inv = 1.0f / sum;
        #pragma unroll
        for (int s = 0; s < T; ++s) att_tr[s * T + r] = e[s] * inv;  // banks r+16(s&1)
    }
    __syncthreads();

    // apply: out[t,col] = sum_s att[t][s] * x[s,col]
    if (tid < 112) {
        const float4* x4 = (const float4*)x;
        float4* o4 = (float4*)out;
        const float4* att4 = (const float4*)att_tr;   // att4[s*4+q] = att[4q..4q+3][s]
        const size_t xbase = ((size_t)(b * T) * C + c) * HW4;
        const size_t tstride = (size_t)C * HW4;
        const int p4 = chunk * 112 + tid;

        // issue ALL 16 x loads upfront: 16 outstanding vmem ops per thread
        float4 xv[16];
        #pragma unroll
        for (int s = 0; s < 16; ++s) xv[s] = x4[xbase + (size_t)s * tstride + p4];

        float4 acc[16];
        #pragma unroll
        for (int t = 0; t < 16; ++t) acc[t] = make_float4(0.f, 0.f, 0.f, 0.f);

        #pragma unroll
        for (int s = 0; s < 16; ++s) {
            #pragma unroll
            for (int q = 0; q < 4; ++q) {
                const float4 a = att4[s * 4 + q];     // broadcast ds_read_b128
                acc[q*4+0].x = fmaf(a.x, xv[s].x, acc[q*4+0].x);
                acc[q*4+0].y = fmaf(a.x, xv[s].y, acc[q*4+0].y);
                acc[q*4+0].z = fmaf(a.x, xv[s].z, acc[q*4+0].z);
                acc[q*4+0].w = fmaf(a.x, xv[s].w, acc[q*4+0].w);
                acc[q*4+1].x = fmaf(a.y, xv[s].x, acc[q*4+1].x);
                acc[q*4+1].y = fmaf(a.y, xv[s].y, acc[q*4+1].y);
                acc[q*4+1].z = fmaf(a.y, xv[s].z, acc[q*4+1].z);
                acc[q*4+1].w = fmaf(a.y, xv[s].w, acc[q*4+1].w);
                acc[q*4+2].x = fmaf(a.z, xv[s].x, acc[q*4+2].x);
                acc[q*4+2].y = fmaf(a.z, xv[s].y, acc[q*4+2].y);
                acc[q*4+2].z = fmaf(a.z, xv[s].z, acc[q*4+2].z);
                acc[q*4+2].w = fmaf(a.z, xv[s].w, acc[q*4+2].w);
                acc[q*4+3].x = fmaf(a.w, xv[s].x, acc[q*4+3].x);
                acc[q*4+3].y = fmaf(a.w, xv[s].y, acc[q*4+3].y);
                acc[q*4+3].z = fmaf(a.w, xv[s].z, acc[q*4+3].z);
                acc[q*4+3].w = fmaf(a.w, xv[s].w, acc[q*4+3].w);
            }
        }

        #pragma unroll
        for (int t = 0; t < 16; ++t) {
            vfloat4* dst = (vfloat4*)&o4[xbase + (size_t)t * tstride + p4];
            vfloat4 v; v.x = acc[t].x; v.y = acc[t].y; v.z = acc[t].z; v.w = acc[t].w;
            __builtin_nontemporal_store(v, dst);
        }
    }
}

extern "C" void kernel_launch(void* const* d_in, const int* in_sizes, int n_in,
                              void* d_out, int out_size, void* d_ws, size_t ws_size,
                              hipStream_t stream) {
    const float* x  = (const float*)d_in[0];
    const float* Wq = (const float*)d_in[1];
    const float* bq = (const float*)d_in[2];
    const float* Wk = (const float*)d_in[3];
    const float* bk = (const float*)d_in[4];
    float* out = (float*)d_out;

    // pooled (2 MB) in workspace — must NOT alias out (apply writes out in
    // the same kernel that reads pooled).
    float* pooled_g = (float*)d_ws;

    pool_kernel<<<dim3(BC, T), dim3(256), 0, stream>>>(x, pooled_g);
    att_apply_kernel<<<dim3(BC, 7), dim3(128), 0, stream>>>(x, pooled_g, Wq, bq, Wk, bk, out);
}

// Round 9
// 211.152 us; speedup vs baseline: 1.0879x; 1.0738x over previous
//
#include <hip/hip_runtime.h>
#include <math.h>

#define B  8
#define T  16
#define C  64
#define H  56
#define W  56
#define HW (H*W)          // 3136
#define HW4 (HW/4)        // 784
#define DS 8
#define DIN (DS*DS)       // 64
#define DOUT 32
#define BC (B*C)          // 512
#define NCOL (BC*HW4)     // 401408 flat float4-columns

typedef float vfloat4 __attribute__((ext_vector_type(4)));

// ---------------------------------------------------------------------------
// R8 -> R9: ILP/MLP changes were neutral (R6, R8); apply stuck at ~62 us vs
// ~25 us floor with Occupancy 26% and only ~10 us of VALU issue -> stalled
// with too few resident waves. This round maximizes true TLP:
//  - 3-kernel split again (R6: split<->fused neutral; K2 ~4 us) so apply has
//    NO serial q/k/softmax prologue gating its memory phase.
//  - K3: flat grid-stride over all 401408 float4-cols, 1568 blocks x 256 thr,
//    EVERY lane owns exactly one column (no dead lanes). att precomputed &
//    loaded as 2 floats/thread (block spans <=2 n's; both panels in LDS,
//    1 KB apart -> same-bank 2-way alias = free). ~50 VGPR, 2 KB LDS ->
//    ALL ~24.5 waves/CU of work resident at once.
//  - normal (cached) stores instead of NT: the 6.7 TB/s fills use cached
//    stores; L3 (256 MB) holds x + out.
// ---------------------------------------------------------------------------

// K1: pool. Block per (n,t): 8192 blocks x 256 thr, 13.5 KB LDS.
// Stage one t-slice (12.25 KB); wave q handles rows {2q,2q+1} (q<3) or {6}
// (q=3) of every 7x7 window -> wave-uniform; xs reads 2-way bank-aliased
// (free). Partials combined via 1 KB LDS. ~18 us ~= its 16 us floor.
__global__ __launch_bounds__(256) void pool_kernel(const float* __restrict__ x,
                                                   float* __restrict__ pooled_g) {
    __shared__ float xs[HW];      // 12544 B
    __shared__ float part[256];   // 1 KB
    const int n = blockIdx.x;     // b*C + c
    const int t = blockIdx.y;
    const int tid = threadIdx.x;
    const int b = n >> 6;
    const int c = n & 63;

    const float4* x4 = (const float4*)x;
    float4* xs4 = (float4*)xs;
    const size_t base = ((size_t)(b * T + t) * C + c) * HW4;

    for (int i = tid; i < HW4; i += 256) xs4[i] = x4[base + i];
    __syncthreads();

    {
        const int wi = tid & 63;      // window = ri*8+rj
        const int q  = tid >> 6;      // wave index -> row group (uniform)
        const int ri = wi >> 3;
        const int rj = wi & 7;
        const int r0 = 2 * q;
        const int nrows = (q < 3) ? 2 : 1;
        float s = 0.f;
        for (int dr = 0; dr < nrows; ++dr) {
            const int row = 7 * ri + r0 + dr;
            const int col0 = 7 * rj;
            #pragma unroll
            for (int dj = 0; dj < 7; ++dj) s += xs[row * W + col0 + dj];
        }
        part[q * 64 + wi] = s;
    }
    __syncthreads();

    if (tid < 64) {
        const float v = part[tid] + part[tid + 64] + part[tid + 128] + part[tid + 192];
        pooled_g[((size_t)n * T + t) * DIN + tid] = v * (1.0f / 49.0f);
    }
}

// K2: q/k + logits + softmax per n. 512 blocks x 256 thr (glue; inputs
// L2/L3-hot). Writes att TRANSPOSED to global: att_g[n][s*16+t].
__global__ __launch_bounds__(256) void att_kernel(const float* __restrict__ pooled_g,
                                                  const float* __restrict__ Wq,
                                                  const float* __restrict__ bq,
                                                  const float* __restrict__ Wk,
                                                  const float* __restrict__ bk,
                                                  float* __restrict__ att_g) {
    __shared__ float pooled_s[T * DIN];   // 4 KB
    __shared__ float qs[T * 33];
    __shared__ float ks[T * 33];
    __shared__ float att_s[T * T];

    const int n = blockIdx.x;
    const int tid = threadIdx.x;

    for (int e = tid; e < T * DIN; e += 256) pooled_s[e] = pooled_g[(size_t)n * (T * DIN) + e];
    __syncthreads();

    for (int e = tid; e < T * DOUT; e += 256) {
        const int t = e >> 5;
        const int d = e & 31;
        float sq = bq[d];
        float sk = bk[d];
        #pragma unroll 8
        for (int kk = 0; kk < DIN; ++kk) {
            const float f = pooled_s[t * DIN + kk];
            sq = fmaf(f, Wq[kk * DOUT + d], sq);
            sk = fmaf(f, Wk[kk * DOUT + d], sk);
        }
        qs[t * 33 + d] = sq;
        ks[t * 33 + d] = sk;
    }
    __syncthreads();

    {
        const int tt = tid >> 4;
        const int ss = tid & 15;
        float s = 0.f;
        #pragma unroll
        for (int d = 0; d < DOUT; ++d) s = fmaf(qs[tt * 33 + d], ks[ss * 33 + d], s);
        att_s[tid] = s * 0.25f;           // 1/sqrt(16)
    }
    __syncthreads();

    if (tid < T) {
        const int r = tid;
        float m = -INFINITY;
        #pragma unroll
        for (int s = 0; s < T; ++s) m = fmaxf(m, att_s[r * T + s]);
        float e[T];
        float sum = 0.f;
        #pragma unroll
        for (int s = 0; s < T; ++s) { e[s] = __expf(att_s[r * T + s] - m); sum += e[s]; }
        const float inv = 1.0f / sum;
        #pragma unroll
        for (int s = 0; s < T; ++s) att_g[(size_t)n * (T * T) + s * T + r] = e[s] * inv;  // transposed
    }
}

// K3: apply, flat-column grid-stride. 1568 blocks x 256 thr = exactly one
// thread per float4-column. out[t,col] = sum_s att_tr[n][s][t] * x[s,col].
// Block spans <=2 n's: both att panels staged in LDS (2 floats/thread).
// No xv hoist (R8: neutral) -> low VGPR -> all work-waves resident.
__global__ __launch_bounds__(256) void apply_kernel(const float* __restrict__ x,
                                                    const float* __restrict__ att_g,
                                                    float* __restrict__ out) {
    __shared__ float att_lds[2 * 256];    // two att panels (maybe identical)
    const int tid = threadIdx.x;
    const int blk0 = blockIdx.x << 8;     // first flat column of this block
    const int n0 = blk0 / HW4;            // const-divisor -> magic mul
    const int n1 = (blk0 + 255) / HW4;

    att_lds[tid]       = att_g[(size_t)n0 * 256 + tid];
    att_lds[256 + tid] = att_g[(size_t)n1 * 256 + tid];
    __syncthreads();

    const int Wf  = blk0 + tid;           // flat column id
    const int n   = Wf / HW4;
    const int col = Wf - n * HW4;
    const int b   = n >> 6;
    const int c   = n & 63;
    const float* att_p = att_lds + ((n != n0) ? 256 : 0);
    const float4* att4 = (const float4*)att_p;   // att4[s*4+q] = att[t=4q..4q+3][s]

    const float4* x4 = (const float4*)x;
    float4* o4 = (float4*)out;
    const size_t xbase = ((size_t)b * T * C + c) * HW4 + col;
    const size_t tstride = (size_t)C * HW4;      // 50176

    float4 acc[16];
    #pragma unroll
    for (int t = 0; t < 16; ++t) acc[t] = make_float4(0.f, 0.f, 0.f, 0.f);

    #pragma unroll 4
    for (int s = 0; s < T; ++s) {
        const float4 xv = x4[xbase + (size_t)s * tstride];
        #pragma unroll
        for (int q = 0; q < 4; ++q) {
            const float4 a = att4[s * 4 + q];    // 2-way same-bank alias max (free)
            acc[q*4+0].x = fmaf(a.x, xv.x, acc[q*4+0].x);
            acc[q*4+0].y = fmaf(a.x, xv.y, acc[q*4+0].y);
            acc[q*4+0].z = fmaf(a.x, xv.z, acc[q*4+0].z);
            acc[q*4+0].w = fmaf(a.x, xv.w, acc[q*4+0].w);
            acc[q*4+1].x = fmaf(a.y, xv.x, acc[q*4+1].x);
            acc[q*4+1].y = fmaf(a.y, xv.y, acc[q*4+1].y);
            acc[q*4+1].z = fmaf(a.y, xv.z, acc[q*4+1].z);
            acc[q*4+1].w = fmaf(a.y, xv.w, acc[q*4+1].w);
            acc[q*4+2].x = fmaf(a.z, xv.x, acc[q*4+2].x);
            acc[q*4+2].y = fmaf(a.z, xv.y, acc[q*4+2].y);
            acc[q*4+2].z = fmaf(a.z, xv.z, acc[q*4+2].z);
            acc[q*4+2].w = fmaf(a.z, xv.w, acc[q*4+2].w);
            acc[q*4+3].x = fmaf(a.w, xv.x, acc[q*4+3].x);
            acc[q*4+3].y = fmaf(a.w, xv.y, acc[q*4+3].y);
            acc[q*4+3].z = fmaf(a.w, xv.z, acc[q*4+3].z);
            acc[q*4+3].w = fmaf(a.w, xv.w, acc[q*4+3].w);
        }
    }

    #pragma unroll
    for (int t = 0; t < 16; ++t) {
        o4[xbase + (size_t)t * tstride] = acc[t];   // cached stores (no NT)
    }
}

extern "C" void kernel_launch(void* const* d_in, const int* in_sizes, int n_in,
                              void* d_out, int out_size, void* d_ws, size_t ws_size,
                              hipStream_t stream) {
    const float* x  = (const float*)d_in[0];
    const float* Wq = (const float*)d_in[1];
    const float* bq = (const float*)d_in[2];
    const float* Wk = (const float*)d_in[3];
    const float* bk = (const float*)d_in[4];
    float* out = (float*)d_out;

    // pooled (2 MB) in the head of out (scratch until K3 overwrites; K2
    // consumes it first — stream-ordered). att (512 KB) in workspace.
    float* pooled_g = out;
    float* att_g = (float*)d_ws;

    pool_kernel<<<dim3(BC, T), dim3(256), 0, stream>>>(x, pooled_g);
    att_kernel<<<dim3(BC), dim3(256), 0, stream>>>(pooled_g, Wq, bq, Wk, bk, att_g);
    apply_kernel<<<dim3(NCOL / 256), dim3(256), 0, stream>>>(x, att_g, out);
}